// Round 25
// baseline (386.544 us; speedup 1.0000x reference)
//
#include <hip/hip_runtime.h>

typedef __attribute__((ext_vector_type(8))) short bf16x8;
typedef __attribute__((ext_vector_type(16))) float f32x16;

#define CPs  72          // shorts per t-row (64 c + 8 pad): 144B pitch, 16B-aligned b128 frags
#define ROWS 130         // 128 t + 2 halo
#define SLOT (ROWS * CPs)
#define FPB  16          // f rows swept per block (prologue amortized 2x vs R18)

__device__ __forceinline__ unsigned short f2bf(float v) {
    unsigned u = __builtin_bit_cast(unsigned, v);
    return (unsigned short)((u + 0x7fffu + ((u >> 16) & 1u)) >> 16);
}

__device__ __forceinline__ float dampf(float tt) {
    return (1.0f - 0.1f * fabsf(tt - 128.f) * (1.f / 128.f))
         * (1.0f - 0.1f * fabsf(tt - 64.f) * (1.f / 64.f));
}

// ---- W reorder: [o][c][kh][kw] f32 -> [k9][o][c] bf16 ----
__global__ __launch_bounds__(256) void prep_w(const float* __restrict__ W,
                                              unsigned short* __restrict__ Wr) {
    int id = blockIdx.x * 256 + threadIdx.x;
    if (id >= 9 * 128 * 64) return;
    int c = id & 63, o = (id >> 6) & 127, k9 = id >> 13;
    Wr[id] = f2bf(W[(o * 64 + c) * 9 + k9]);
}

// ---- main conv: R18 structure (champion, 281 us) with two tweaks:
//      (a) FPB=16 (half the prologues), (b) write_row moved BEFORE the
//      epilogue so the final barrier overlaps the 64 global stores ----
__global__ __launch_bounds__(256) void damp_conv_mfma(
    const float* __restrict__ x, const unsigned short* __restrict__ Wr,
    const float* __restrict__ b, float* __restrict__ out)
{
    __shared__ unsigned short xs[3 * SLOT];   // 56,160 B

    const int tid  = threadIdx.x;
    const int lane = tid & 63;
    const int wid  = tid >> 6;
    const int q    = lane & 3;
    const int p16  = lane >> 2;
    const int lo32 = lane & 31;
    const int kg   = lane >> 5;    // k-group (8 elems) within fragment

    const int raw = blockIdx.x;                        // grid 512
    const int logical = (raw & 7) * 64 + (raw >> 3);   // XCD-chunked, bijective (512%8==0)
    const int n  = logical >> 4;
    const int th = (logical >> 3) & 1;
    const int f0 = (logical & 7) * FPB;

    const int tb = th * 128;
    const int oh = wid & 1;       // wave o-half
    const int tw = wid >> 1;      // wave t-half within window

    const unsigned selv = (q & 1) ? 0x07060302u : 0x05040100u;

    float dmp[2][4];
    #pragma unroll
    for (int s = 0; s < 2; ++s)
        #pragma unroll
        for (int j = 0; j < 4; ++j)
            dmp[s][j] = dampf((float)(tb + 64 * s + 4 * p16 + j));

    // halo lanes: tid<128 covers side=(tid>>6)&1, c=tid&63
    const int hside = (tid >> 6) & 1;
    const int hc    = tid & 63;
    const int t_h   = tb + (hside ? 128 : -1);
    const bool tok  = (unsigned)t_h < 256u;
    const float dmp_h = dampf((float)(tok ? t_h : 0));

    float4 rb[8];
    float  hv;

    auto issue_row = [&](int fg) {
        const bool fok = (unsigned)fg < 128u;   // wave-uniform
        #pragma unroll
        for (int j = 0; j < 8; ++j) {
            int c = wid * 16 + (j & 3) * 4 + q;
            const float* src = x + ((size_t)(n * 64 + c) * 128 + (fok ? fg : 0)) * 256
                             + tb + (j >> 2) * 64 + 4 * p16;
            rb[j] = fok ? *(const float4*)src : (float4){0.f, 0.f, 0.f, 0.f};
        }
        hv = 0.f;
        if (tid < 128 && fok && tok)
            hv = x[((size_t)(n * 64 + hc) * 128 + fg) * 256 + t_h];
    };

    auto write_row = [&](int slot) {
        unsigned short* dstb = &xs[slot * SLOT];
        #pragma unroll
        for (int j = 0; j < 8; ++j) {
            const int s  = j >> 2;
            const int c0 = wid * 16 + (j & 3) * 4;
            float4 v = rb[j];
            unsigned d0 = (unsigned)f2bf(v.x * dmp[s][0]) | ((unsigned)f2bf(v.y * dmp[s][1]) << 16);
            unsigned d1 = (unsigned)f2bf(v.z * dmp[s][2]) | ((unsigned)f2bf(v.w * dmp[s][3]) << 16);
            // 4x4 u16 quad transpose: lane ends with c0..c0+3 at t_loc = 64s + lane
            unsigned p0 = __shfl_xor((int)d0, 2);
            unsigned p1 = __shfl_xor((int)d1, 2);
            bool hi = (lane >> 1) & 1;
            unsigned own = hi ? d1 : d0;
            unsigned oth = hi ? p1 : p0;
            unsigned sown = __shfl_xor((int)own, 1);
            unsigned soth = __shfl_xor((int)oth, 1);
            bool b0 = q & 1, b1 = q & 2;
            unsigned a0 = b0 ? sown : own, a1 = b0 ? own : sown;
            unsigned g0 = b0 ? soth : oth, g1 = b0 ? oth : soth;
            unsigned e0 = b1 ? g0 : a0, e1 = b1 ? g1 : a1;
            unsigned e2 = b1 ? a0 : g0, e3 = b1 ? a1 : g1;
            unsigned r0 = __builtin_amdgcn_perm(e1, e0, selv);
            unsigned r1 = __builtin_amdgcn_perm(e3, e2, selv);
            unsigned* dst = (unsigned*)&dstb[(1 + 64 * s + lane) * CPs + c0];
            dst[0] = r0;
            dst[1] = r1;
        }
        if (tid < 128)
            dstb[(hside ? (ROWS - 1) : 0) * CPs + hc] = f2bf(hv * dmp_h);
    };

    f32x16 acc[2][2];

    auto mfma_kh = [&](int kh, int slot) {
        const unsigned short* sb = &xs[slot * SLOT];
        #pragma unroll
        for (int kw = 0; kw < 3; ++kw) {
            #pragma unroll
            for (int ks = 0; ks < 4; ++ks) {          // K-step: 16 c per MFMA
                const int cb = ks * 16 + kg * 8;      // this lane's 8-c base
                bf16x8 af[2];
                #pragma unroll
                for (int fm = 0; fm < 2; ++fm) {
                    int o = oh * 64 + fm * 32 + lo32;
                    af[fm] = *(const bf16x8*)(Wr + (((kh * 3 + kw) * 128 + o) << 6) + cb);
                }
                #pragma unroll
                for (int fn = 0; fn < 2; ++fn) {
                    int row = tw * 64 + fn * 32 + lo32 + kw;
                    // single 16B-aligned ds_read_b128 (R17-verified conflict-free)
                    bf16x8 bx = *(const bf16x8*)&sb[row * CPs + cb];
                    #pragma unroll
                    for (int fm = 0; fm < 2; ++fm)
                        acc[fm][fn] = __builtin_amdgcn_mfma_f32_32x32x16_bf16(
                            af[fm], bx, acc[fm][fn], 0, 0, 0);
                }
            }
        }
    };

    // ---- prologue: stage rows f0-1, f0, f0+1 into slots 0,1,2 ----
    issue_row(f0 - 1); write_row(0);
    issue_row(f0);     write_row(1);
    issue_row(f0 + 1); write_row(2);
    __syncthreads();

    int sA = 0, sB = 1, sC = 2;   // slots of rows f-1, f, f+1

    #pragma unroll 1
    for (int i = 0; i < FPB; ++i) {
        const int f = f0 + i;
        if (i < FPB - 1) issue_row(f + 2);   // loads in flight under this iter's MFMAs

        #pragma unroll
        for (int a = 0; a < 2; ++a)
            #pragma unroll
            for (int c2 = 0; c2 < 2; ++c2)
                #pragma unroll
                for (int e = 0; e < 16; ++e) acc[a][c2][e] = 0.f;

        mfma_kh(0, sA);
        mfma_kh(1, sB);
        mfma_kh(2, sC);

        __syncthreads();                       // all waves done reading slot sA
        if (i < FPB - 1) write_row(sA);        // row f+2 replaces row f-1 (before epilogue)

        // epilogue: C/D col=lane&31 (t), row=(reg&3)+8*(reg>>2)+4*(lane>>5);
        // runs between the write and the barrier -> barrier wait overlaps stores
        #pragma unroll
        for (int fm = 0; fm < 2; ++fm) {
            #pragma unroll
            for (int fn = 0; fn < 2; ++fn) {
                int t = tb + tw * 64 + fn * 32 + lo32;
                #pragma unroll
                for (int reg = 0; reg < 16; ++reg) {
                    int o = oh * 64 + fm * 32 + (reg & 3) + 8 * (reg >> 2) + 4 * kg;
                    out[(((size_t)n * 128 + o) * 128 + f) * 256 + t] = acc[fm][fn][reg] + b[o];
                }
            }
        }

        __syncthreads();                       // ring slot ready for next iter
        int tmp = sA; sA = sB; sB = sC; sC = tmp;
    }
}

extern "C" void kernel_launch(void* const* d_in, const int* in_sizes, int n_in,
                              void* d_out, int out_size, void* d_ws, size_t ws_size,
                              hipStream_t stream) {
    const float* x = (const float*)d_in[0];
    const float* W = (const float*)d_in[1];
    const float* b = (const float*)d_in[2];
    float* out = (float*)d_out;
    unsigned short* Wr = (unsigned short*)d_ws;  // 147,456 B

    hipLaunchKernelGGL(prep_w, dim3(288), dim3(256), 0, stream, W, Wr);
    hipLaunchKernelGGL(damp_conv_mfma, dim3(512), dim3(256), 0, stream, x, Wr, b, out);
}

// Round 26
// 280.913 us; speedup vs baseline: 1.3760x; 1.3760x over previous
//
#include <hip/hip_runtime.h>

typedef __attribute__((ext_vector_type(8))) short bf16x8;
typedef __attribute__((ext_vector_type(16))) float f32x16;

#define CPs  72          // shorts per t-row (64 c + 8 pad): 144B pitch, 16B-aligned b128 frags
#define ROWS 130         // 128 t + 2 halo
#define SLOT (ROWS * CPs)
#define FPB  8           // f rows swept per block

__device__ __forceinline__ unsigned short f2bf(float v) {
    unsigned u = __builtin_bit_cast(unsigned, v);
    return (unsigned short)((u + 0x7fffu + ((u >> 16) & 1u)) >> 16);
}

__device__ __forceinline__ float dampf(float tt) {
    return (1.0f - 0.1f * fabsf(tt - 128.f) * (1.f / 128.f))
         * (1.0f - 0.1f * fabsf(tt - 64.f) * (1.f / 64.f));
}

// ---- W reorder: [o][c][kh][kw] f32 -> [k9][o][c] bf16 ----
__global__ __launch_bounds__(256) void prep_w(const float* __restrict__ W,
                                              unsigned short* __restrict__ Wr) {
    int id = blockIdx.x * 256 + threadIdx.x;
    if (id >= 9 * 128 * 64) return;
    int c = id & 63, o = (id >> 6) & 127, k9 = id >> 13;
    Wr[id] = f2bf(W[(o * 64 + c) * 9 + k9]);
}

// ---- main conv: R18 champion structure (281 us), exact revert.
//      32x32x16 MFMA, 3-slot ring, 2 barriers/iter, f-loop rolled,
//      taps unrolled, CPs=72 single-b128 fragments (0 conflicts, R17) ----
__global__ __launch_bounds__(256) void damp_conv_mfma(
    const float* __restrict__ x, const unsigned short* __restrict__ Wr,
    const float* __restrict__ b, float* __restrict__ out)
{
    __shared__ unsigned short xs[3 * SLOT];   // 56,160 B

    const int tid  = threadIdx.x;
    const int lane = tid & 63;
    const int wid  = tid >> 6;
    const int q    = lane & 3;
    const int p16  = lane >> 2;
    const int lo32 = lane & 31;
    const int kg   = lane >> 5;    // k-group (8 elems) within fragment

    const int raw = blockIdx.x;
    const int logical = (raw & 7) * 128 + (raw >> 3);   // XCD-chunked, bijective
    const int n  = logical >> 5;
    const int th = (logical >> 4) & 1;
    const int f0 = (logical & 15) * FPB;

    const int tb = th * 128;
    const int oh = wid & 1;       // wave o-half
    const int tw = wid >> 1;      // wave t-half within window

    const unsigned selv = (q & 1) ? 0x07060302u : 0x05040100u;

    float dmp[2][4];
    #pragma unroll
    for (int s = 0; s < 2; ++s)
        #pragma unroll
        for (int j = 0; j < 4; ++j)
            dmp[s][j] = dampf((float)(tb + 64 * s + 4 * p16 + j));

    // halo lanes: tid<128 covers side=(tid>>6)&1, c=tid&63
    const int hside = (tid >> 6) & 1;
    const int hc    = tid & 63;
    const int t_h   = tb + (hside ? 128 : -1);
    const bool tok  = (unsigned)t_h < 256u;
    const float dmp_h = dampf((float)(tok ? t_h : 0));

    float4 rb[8];
    float  hv;

    auto issue_row = [&](int fg) {
        const bool fok = (unsigned)fg < 128u;   // wave-uniform
        #pragma unroll
        for (int j = 0; j < 8; ++j) {
            int c = wid * 16 + (j & 3) * 4 + q;
            const float* src = x + ((size_t)(n * 64 + c) * 128 + (fok ? fg : 0)) * 256
                             + tb + (j >> 2) * 64 + 4 * p16;
            rb[j] = fok ? *(const float4*)src : (float4){0.f, 0.f, 0.f, 0.f};
        }
        hv = 0.f;
        if (tid < 128 && fok && tok)
            hv = x[((size_t)(n * 64 + hc) * 128 + fg) * 256 + t_h];
    };

    auto write_row = [&](int slot) {
        unsigned short* dstb = &xs[slot * SLOT];
        #pragma unroll
        for (int j = 0; j < 8; ++j) {
            const int s  = j >> 2;
            const int c0 = wid * 16 + (j & 3) * 4;
            float4 v = rb[j];
            unsigned d0 = (unsigned)f2bf(v.x * dmp[s][0]) | ((unsigned)f2bf(v.y * dmp[s][1]) << 16);
            unsigned d1 = (unsigned)f2bf(v.z * dmp[s][2]) | ((unsigned)f2bf(v.w * dmp[s][3]) << 16);
            // 4x4 u16 quad transpose: lane ends with c0..c0+3 at t_loc = 64s + lane
            unsigned p0 = __shfl_xor((int)d0, 2);
            unsigned p1 = __shfl_xor((int)d1, 2);
            bool hi = (lane >> 1) & 1;
            unsigned own = hi ? d1 : d0;
            unsigned oth = hi ? p1 : p0;
            unsigned sown = __shfl_xor((int)own, 1);
            unsigned soth = __shfl_xor((int)oth, 1);
            bool b0 = q & 1, b1 = q & 2;
            unsigned a0 = b0 ? sown : own, a1 = b0 ? own : sown;
            unsigned g0 = b0 ? soth : oth, g1 = b0 ? oth : soth;
            unsigned e0 = b1 ? g0 : a0, e1 = b1 ? g1 : a1;
            unsigned e2 = b1 ? a0 : g0, e3 = b1 ? a1 : g1;
            unsigned r0 = __builtin_amdgcn_perm(e1, e0, selv);
            unsigned r1 = __builtin_amdgcn_perm(e3, e2, selv);
            unsigned* dst = (unsigned*)&dstb[(1 + 64 * s + lane) * CPs + c0];
            dst[0] = r0;
            dst[1] = r1;
        }
        if (tid < 128)
            dstb[(hside ? (ROWS - 1) : 0) * CPs + hc] = f2bf(hv * dmp_h);
    };

    f32x16 acc[2][2];

    auto mfma_kh = [&](int kh, int slot) {
        const unsigned short* sb = &xs[slot * SLOT];
        #pragma unroll
        for (int kw = 0; kw < 3; ++kw) {
            #pragma unroll
            for (int ks = 0; ks < 4; ++ks) {          // K-step: 16 c per MFMA
                const int cb = ks * 16 + kg * 8;      // this lane's 8-c base
                bf16x8 af[2];
                #pragma unroll
                for (int fm = 0; fm < 2; ++fm) {
                    int o = oh * 64 + fm * 32 + lo32;
                    af[fm] = *(const bf16x8*)(Wr + (((kh * 3 + kw) * 128 + o) << 6) + cb);
                }
                #pragma unroll
                for (int fn = 0; fn < 2; ++fn) {
                    int row = tw * 64 + fn * 32 + lo32 + kw;
                    // single 16B-aligned ds_read_b128 (R17-verified conflict-free)
                    bf16x8 bx = *(const bf16x8*)&sb[row * CPs + cb];
                    #pragma unroll
                    for (int fm = 0; fm < 2; ++fm)
                        acc[fm][fn] = __builtin_amdgcn_mfma_f32_32x32x16_bf16(
                            af[fm], bx, acc[fm][fn], 0, 0, 0);
                }
            }
        }
    };

    // ---- prologue: stage rows f0-1, f0, f0+1 into slots 0,1,2 ----
    issue_row(f0 - 1); write_row(0);
    issue_row(f0);     write_row(1);
    issue_row(f0 + 1); write_row(2);
    __syncthreads();

    int sA = 0, sB = 1, sC = 2;   // slots of rows f-1, f, f+1

    #pragma unroll 1
    for (int i = 0; i < FPB; ++i) {
        const int f = f0 + i;
        if (i < FPB - 1) issue_row(f + 2);   // loads in flight under this iter's MFMAs

        #pragma unroll
        for (int a = 0; a < 2; ++a)
            #pragma unroll
            for (int c2 = 0; c2 < 2; ++c2)
                #pragma unroll
                for (int e = 0; e < 16; ++e) acc[a][c2][e] = 0.f;

        mfma_kh(0, sA);
        mfma_kh(1, sB);
        mfma_kh(2, sC);

        // epilogue: C/D layout col=lane&31 (t), row=(reg&3)+8*(reg>>2)+4*(lane>>5)
        #pragma unroll
        for (int fm = 0; fm < 2; ++fm) {
            #pragma unroll
            for (int fn = 0; fn < 2; ++fn) {
                int t = tb + tw * 64 + fn * 32 + lo32;
                #pragma unroll
                for (int reg = 0; reg < 16; ++reg) {
                    int o = oh * 64 + fm * 32 + (reg & 3) + 8 * (reg >> 2) + 4 * kg;
                    out[(((size_t)n * 128 + o) * 128 + f) * 256 + t] = acc[fm][fn][reg] + b[o];
                }
            }
        }

        __syncthreads();                       // all waves done reading slot sA
        if (i < FPB - 1) write_row(sA);        // row f+2 replaces row f-1
        __syncthreads();                       // ring slot ready for next iter
        int tmp = sA; sA = sB; sB = sC; sC = tmp;
    }
}

extern "C" void kernel_launch(void* const* d_in, const int* in_sizes, int n_in,
                              void* d_out, int out_size, void* d_ws, size_t ws_size,
                              hipStream_t stream) {
    const float* x = (const float*)d_in[0];
    const float* W = (const float*)d_in[1];
    const float* b = (const float*)d_in[2];
    float* out = (float*)d_out;
    unsigned short* Wr = (unsigned short*)d_ws;  // 147,456 B

    hipLaunchKernelGGL(prep_w, dim3(288), dim3(256), 0, stream, W, Wr);
    hipLaunchKernelGGL(damp_conv_mfma, dim3(1024), dim3(256), 0, stream, x, Wr, b, out);
}

// Round 27
// 257.808 us; speedup vs baseline: 1.4993x; 1.0896x over previous
//
#include <hip/hip_runtime.h>

typedef __attribute__((ext_vector_type(8))) short bf16x8;
typedef __attribute__((ext_vector_type(16))) float f32x16;

#define CPs  72          // shorts per t-row (64 c + 8 pad): 144B pitch, 16B-aligned b128 frags
#define ROWS 130         // 128 t + 2 halo
#define SLOT (ROWS * CPs)
#define FPB  16          // f rows swept per block (ONLY change vs R26; body identical)

__device__ __forceinline__ unsigned short f2bf(float v) {
    unsigned u = __builtin_bit_cast(unsigned, v);
    return (unsigned short)((u + 0x7fffu + ((u >> 16) & 1u)) >> 16);
}

__device__ __forceinline__ float dampf(float tt) {
    return (1.0f - 0.1f * fabsf(tt - 128.f) * (1.f / 128.f))
         * (1.0f - 0.1f * fabsf(tt - 64.f) * (1.f / 64.f));
}

// ---- W reorder: [o][c][kh][kw] f32 -> [k9][o][c] bf16 ----
__global__ __launch_bounds__(256) void prep_w(const float* __restrict__ W,
                                              unsigned short* __restrict__ Wr) {
    int id = blockIdx.x * 256 + threadIdx.x;
    if (id >= 9 * 128 * 64) return;
    int c = id & 63, o = (id >> 6) & 127, k9 = id >> 13;
    Wr[id] = f2bf(W[(o * 64 + c) * 9 + k9]);
}

// ---- main conv: R26 champion body, FPB=16 (prologue amortized 2x).
//      32x32x16 MFMA, 3-slot ring, 2 barriers/iter, f-loop rolled,
//      taps unrolled, CPs=72 single-b128 fragments (0 conflicts, R17) ----
__global__ __launch_bounds__(256) void damp_conv_mfma(
    const float* __restrict__ x, const unsigned short* __restrict__ Wr,
    const float* __restrict__ b, float* __restrict__ out)
{
    __shared__ unsigned short xs[3 * SLOT];   // 56,160 B

    const int tid  = threadIdx.x;
    const int lane = tid & 63;
    const int wid  = tid >> 6;
    const int q    = lane & 3;
    const int p16  = lane >> 2;
    const int lo32 = lane & 31;
    const int kg   = lane >> 5;    // k-group (8 elems) within fragment

    const int raw = blockIdx.x;                        // grid 512
    const int logical = (raw & 7) * 64 + (raw >> 3);   // XCD-chunked, bijective (512%8==0)
    const int n  = logical >> 4;
    const int th = (logical >> 3) & 1;
    const int f0 = (logical & 7) * FPB;

    const int tb = th * 128;
    const int oh = wid & 1;       // wave o-half
    const int tw = wid >> 1;      // wave t-half within window

    const unsigned selv = (q & 1) ? 0x07060302u : 0x05040100u;

    float dmp[2][4];
    #pragma unroll
    for (int s = 0; s < 2; ++s)
        #pragma unroll
        for (int j = 0; j < 4; ++j)
            dmp[s][j] = dampf((float)(tb + 64 * s + 4 * p16 + j));

    // halo lanes: tid<128 covers side=(tid>>6)&1, c=tid&63
    const int hside = (tid >> 6) & 1;
    const int hc    = tid & 63;
    const int t_h   = tb + (hside ? 128 : -1);
    const bool tok  = (unsigned)t_h < 256u;
    const float dmp_h = dampf((float)(tok ? t_h : 0));

    float4 rb[8];
    float  hv;

    auto issue_row = [&](int fg) {
        const bool fok = (unsigned)fg < 128u;   // wave-uniform
        #pragma unroll
        for (int j = 0; j < 8; ++j) {
            int c = wid * 16 + (j & 3) * 4 + q;
            const float* src = x + ((size_t)(n * 64 + c) * 128 + (fok ? fg : 0)) * 256
                             + tb + (j >> 2) * 64 + 4 * p16;
            rb[j] = fok ? *(const float4*)src : (float4){0.f, 0.f, 0.f, 0.f};
        }
        hv = 0.f;
        if (tid < 128 && fok && tok)
            hv = x[((size_t)(n * 64 + hc) * 128 + fg) * 256 + t_h];
    };

    auto write_row = [&](int slot) {
        unsigned short* dstb = &xs[slot * SLOT];
        #pragma unroll
        for (int j = 0; j < 8; ++j) {
            const int s  = j >> 2;
            const int c0 = wid * 16 + (j & 3) * 4;
            float4 v = rb[j];
            unsigned d0 = (unsigned)f2bf(v.x * dmp[s][0]) | ((unsigned)f2bf(v.y * dmp[s][1]) << 16);
            unsigned d1 = (unsigned)f2bf(v.z * dmp[s][2]) | ((unsigned)f2bf(v.w * dmp[s][3]) << 16);
            // 4x4 u16 quad transpose: lane ends with c0..c0+3 at t_loc = 64s + lane
            unsigned p0 = __shfl_xor((int)d0, 2);
            unsigned p1 = __shfl_xor((int)d1, 2);
            bool hi = (lane >> 1) & 1;
            unsigned own = hi ? d1 : d0;
            unsigned oth = hi ? p1 : p0;
            unsigned sown = __shfl_xor((int)own, 1);
            unsigned soth = __shfl_xor((int)oth, 1);
            bool b0 = q & 1, b1 = q & 2;
            unsigned a0 = b0 ? sown : own, a1 = b0 ? own : sown;
            unsigned g0 = b0 ? soth : oth, g1 = b0 ? oth : soth;
            unsigned e0 = b1 ? g0 : a0, e1 = b1 ? g1 : a1;
            unsigned e2 = b1 ? a0 : g0, e3 = b1 ? a1 : g1;
            unsigned r0 = __builtin_amdgcn_perm(e1, e0, selv);
            unsigned r1 = __builtin_amdgcn_perm(e3, e2, selv);
            unsigned* dst = (unsigned*)&dstb[(1 + 64 * s + lane) * CPs + c0];
            dst[0] = r0;
            dst[1] = r1;
        }
        if (tid < 128)
            dstb[(hside ? (ROWS - 1) : 0) * CPs + hc] = f2bf(hv * dmp_h);
    };

    f32x16 acc[2][2];

    auto mfma_kh = [&](int kh, int slot) {
        const unsigned short* sb = &xs[slot * SLOT];
        #pragma unroll
        for (int kw = 0; kw < 3; ++kw) {
            #pragma unroll
            for (int ks = 0; ks < 4; ++ks) {          // K-step: 16 c per MFMA
                const int cb = ks * 16 + kg * 8;      // this lane's 8-c base
                bf16x8 af[2];
                #pragma unroll
                for (int fm = 0; fm < 2; ++fm) {
                    int o = oh * 64 + fm * 32 + lo32;
                    af[fm] = *(const bf16x8*)(Wr + (((kh * 3 + kw) * 128 + o) << 6) + cb);
                }
                #pragma unroll
                for (int fn = 0; fn < 2; ++fn) {
                    int row = tw * 64 + fn * 32 + lo32 + kw;
                    // single 16B-aligned ds_read_b128 (R17-verified conflict-free)
                    bf16x8 bx = *(const bf16x8*)&sb[row * CPs + cb];
                    #pragma unroll
                    for (int fm = 0; fm < 2; ++fm)
                        acc[fm][fn] = __builtin_amdgcn_mfma_f32_32x32x16_bf16(
                            af[fm], bx, acc[fm][fn], 0, 0, 0);
                }
            }
        }
    };

    // ---- prologue: stage rows f0-1, f0, f0+1 into slots 0,1,2 ----
    issue_row(f0 - 1); write_row(0);
    issue_row(f0);     write_row(1);
    issue_row(f0 + 1); write_row(2);
    __syncthreads();

    int sA = 0, sB = 1, sC = 2;   // slots of rows f-1, f, f+1

    #pragma unroll 1
    for (int i = 0; i < FPB; ++i) {
        const int f = f0 + i;
        if (i < FPB - 1) issue_row(f + 2);   // loads in flight under this iter's MFMAs

        #pragma unroll
        for (int a = 0; a < 2; ++a)
            #pragma unroll
            for (int c2 = 0; c2 < 2; ++c2)
                #pragma unroll
                for (int e = 0; e < 16; ++e) acc[a][c2][e] = 0.f;

        mfma_kh(0, sA);
        mfma_kh(1, sB);
        mfma_kh(2, sC);

        // epilogue: C/D layout col=lane&31 (t), row=(reg&3)+8*(reg>>2)+4*(lane>>5)
        #pragma unroll
        for (int fm = 0; fm < 2; ++fm) {
            #pragma unroll
            for (int fn = 0; fn < 2; ++fn) {
                int t = tb + tw * 64 + fn * 32 + lo32;
                #pragma unroll
                for (int reg = 0; reg < 16; ++reg) {
                    int o = oh * 64 + fm * 32 + (reg & 3) + 8 * (reg >> 2) + 4 * kg;
                    out[(((size_t)n * 128 + o) * 128 + f) * 256 + t] = acc[fm][fn][reg] + b[o];
                }
            }
        }

        __syncthreads();                       // all waves done reading slot sA
        if (i < FPB - 1) write_row(sA);        // row f+2 replaces row f-1
        __syncthreads();                       // ring slot ready for next iter
        int tmp = sA; sA = sB; sB = sC; sC = tmp;
    }
}

extern "C" void kernel_launch(void* const* d_in, const int* in_sizes, int n_in,
                              void* d_out, int out_size, void* d_ws, size_t ws_size,
                              hipStream_t stream) {
    const float* x = (const float*)d_in[0];
    const float* W = (const float*)d_in[1];
    const float* b = (const float*)d_in[2];
    float* out = (float*)d_out;
    unsigned short* Wr = (unsigned short*)d_ws;  // 147,456 B

    hipLaunchKernelGGL(prep_w, dim3(288), dim3(256), 0, stream, W, Wr);
    hipLaunchKernelGGL(damp_conv_mfma, dim3(512), dim3(256), 0, stream, x, Wr, b, out);
}

// Round 28
// 254.359 us; speedup vs baseline: 1.5197x; 1.0136x over previous
//
#include <hip/hip_runtime.h>

typedef __attribute__((ext_vector_type(8))) short bf16x8;
typedef __attribute__((ext_vector_type(16))) float f32x16;

#define CPs  72          // shorts per t-row (64 c + 8 pad): 144B pitch, 16B-aligned b128 frags
#define ROWS 130         // 128 t + 2 halo
#define SLOT (ROWS * CPs)
#define FPB  32          // f rows swept per block (grid 256 = exactly 1 block/CU)

__device__ __forceinline__ unsigned short f2bf(float v) {
    unsigned u = __builtin_bit_cast(unsigned, v);
    return (unsigned short)((u + 0x7fffu + ((u >> 16) & 1u)) >> 16);
}

__device__ __forceinline__ float dampf(float tt) {
    return (1.0f - 0.1f * fabsf(tt - 128.f) * (1.f / 128.f))
         * (1.0f - 0.1f * fabsf(tt - 64.f) * (1.f / 64.f));
}

// ---- W reorder: [o][c][kh][kw] f32 -> [k9][o][c] bf16 ----
__global__ __launch_bounds__(256) void prep_w(const float* __restrict__ W,
                                              unsigned short* __restrict__ Wr) {
    int id = blockIdx.x * 256 + threadIdx.x;
    if (id >= 9 * 128 * 64) return;
    int c = id & 63, o = (id >> 6) & 127, k9 = id >> 13;
    Wr[id] = f2bf(W[(o * 64 + c) * 9 + k9]);
}

// ---- main conv: R26 champion body, FPB=32 (grid 256, 1 block/CU, zero tail).
//      32x32x16 MFMA, 3-slot ring, 2 barriers/iter, f-loop rolled,
//      taps unrolled, CPs=72 single-b128 fragments (0 conflicts, R17) ----
__global__ __launch_bounds__(256) void damp_conv_mfma(
    const float* __restrict__ x, const unsigned short* __restrict__ Wr,
    const float* __restrict__ b, float* __restrict__ out)
{
    __shared__ unsigned short xs[3 * SLOT];   // 56,160 B

    const int tid  = threadIdx.x;
    const int lane = tid & 63;
    const int wid  = tid >> 6;
    const int q    = lane & 3;
    const int p16  = lane >> 2;
    const int lo32 = lane & 31;
    const int kg   = lane >> 5;    // k-group (8 elems) within fragment

    const int raw = blockIdx.x;                        // grid 256
    const int logical = (raw & 7) * 32 + (raw >> 3);   // XCD-chunked, bijective (256%8==0)
    const int n  = logical >> 3;
    const int th = (logical >> 2) & 1;
    const int f0 = (logical & 3) * FPB;

    const int tb = th * 128;
    const int oh = wid & 1;       // wave o-half
    const int tw = wid >> 1;      // wave t-half within window

    const unsigned selv = (q & 1) ? 0x07060302u : 0x05040100u;

    float dmp[2][4];
    #pragma unroll
    for (int s = 0; s < 2; ++s)
        #pragma unroll
        for (int j = 0; j < 4; ++j)
            dmp[s][j] = dampf((float)(tb + 64 * s + 4 * p16 + j));

    // halo lanes: tid<128 covers side=(tid>>6)&1, c=tid&63
    const int hside = (tid >> 6) & 1;
    const int hc    = tid & 63;
    const int t_h   = tb + (hside ? 128 : -1);
    const bool tok  = (unsigned)t_h < 256u;
    const float dmp_h = dampf((float)(tok ? t_h : 0));

    float4 rb[8];
    float  hv;

    auto issue_row = [&](int fg) {
        const bool fok = (unsigned)fg < 128u;   // wave-uniform
        #pragma unroll
        for (int j = 0; j < 8; ++j) {
            int c = wid * 16 + (j & 3) * 4 + q;
            const float* src = x + ((size_t)(n * 64 + c) * 128 + (fok ? fg : 0)) * 256
                             + tb + (j >> 2) * 64 + 4 * p16;
            rb[j] = fok ? *(const float4*)src : (float4){0.f, 0.f, 0.f, 0.f};
        }
        hv = 0.f;
        if (tid < 128 && fok && tok)
            hv = x[((size_t)(n * 64 + hc) * 128 + fg) * 256 + t_h];
    };

    auto write_row = [&](int slot) {
        unsigned short* dstb = &xs[slot * SLOT];
        #pragma unroll
        for (int j = 0; j < 8; ++j) {
            const int s  = j >> 2;
            const int c0 = wid * 16 + (j & 3) * 4;
            float4 v = rb[j];
            unsigned d0 = (unsigned)f2bf(v.x * dmp[s][0]) | ((unsigned)f2bf(v.y * dmp[s][1]) << 16);
            unsigned d1 = (unsigned)f2bf(v.z * dmp[s][2]) | ((unsigned)f2bf(v.w * dmp[s][3]) << 16);
            // 4x4 u16 quad transpose: lane ends with c0..c0+3 at t_loc = 64s + lane
            unsigned p0 = __shfl_xor((int)d0, 2);
            unsigned p1 = __shfl_xor((int)d1, 2);
            bool hi = (lane >> 1) & 1;
            unsigned own = hi ? d1 : d0;
            unsigned oth = hi ? p1 : p0;
            unsigned sown = __shfl_xor((int)own, 1);
            unsigned soth = __shfl_xor((int)oth, 1);
            bool b0 = q & 1, b1 = q & 2;
            unsigned a0 = b0 ? sown : own, a1 = b0 ? own : sown;
            unsigned g0 = b0 ? soth : oth, g1 = b0 ? oth : soth;
            unsigned e0 = b1 ? g0 : a0, e1 = b1 ? g1 : a1;
            unsigned e2 = b1 ? a0 : g0, e3 = b1 ? a1 : g1;
            unsigned r0 = __builtin_amdgcn_perm(e1, e0, selv);
            unsigned r1 = __builtin_amdgcn_perm(e3, e2, selv);
            unsigned* dst = (unsigned*)&dstb[(1 + 64 * s + lane) * CPs + c0];
            dst[0] = r0;
            dst[1] = r1;
        }
        if (tid < 128)
            dstb[(hside ? (ROWS - 1) : 0) * CPs + hc] = f2bf(hv * dmp_h);
    };

    f32x16 acc[2][2];

    auto mfma_kh = [&](int kh, int slot) {
        const unsigned short* sb = &xs[slot * SLOT];
        #pragma unroll
        for (int kw = 0; kw < 3; ++kw) {
            #pragma unroll
            for (int ks = 0; ks < 4; ++ks) {          // K-step: 16 c per MFMA
                const int cb = ks * 16 + kg * 8;      // this lane's 8-c base
                bf16x8 af[2];
                #pragma unroll
                for (int fm = 0; fm < 2; ++fm) {
                    int o = oh * 64 + fm * 32 + lo32;
                    af[fm] = *(const bf16x8*)(Wr + (((kh * 3 + kw) * 128 + o) << 6) + cb);
                }
                #pragma unroll
                for (int fn = 0; fn < 2; ++fn) {
                    int row = tw * 64 + fn * 32 + lo32 + kw;
                    // single 16B-aligned ds_read_b128 (R17-verified conflict-free)
                    bf16x8 bx = *(const bf16x8*)&sb[row * CPs + cb];
                    #pragma unroll
                    for (int fm = 0; fm < 2; ++fm)
                        acc[fm][fn] = __builtin_amdgcn_mfma_f32_32x32x16_bf16(
                            af[fm], bx, acc[fm][fn], 0, 0, 0);
                }
            }
        }
    };

    // ---- prologue: stage rows f0-1, f0, f0+1 into slots 0,1,2 ----
    issue_row(f0 - 1); write_row(0);
    issue_row(f0);     write_row(1);
    issue_row(f0 + 1); write_row(2);
    __syncthreads();

    int sA = 0, sB = 1, sC = 2;   // slots of rows f-1, f, f+1

    #pragma unroll 1
    for (int i = 0; i < FPB; ++i) {
        const int f = f0 + i;
        if (i < FPB - 1) issue_row(f + 2);   // loads in flight under this iter's MFMAs

        #pragma unroll
        for (int a = 0; a < 2; ++a)
            #pragma unroll
            for (int c2 = 0; c2 < 2; ++c2)
                #pragma unroll
                for (int e = 0; e < 16; ++e) acc[a][c2][e] = 0.f;

        mfma_kh(0, sA);
        mfma_kh(1, sB);
        mfma_kh(2, sC);

        // epilogue: C/D layout col=lane&31 (t), row=(reg&3)+8*(reg>>2)+4*(lane>>5)
        #pragma unroll
        for (int fm = 0; fm < 2; ++fm) {
            #pragma unroll
            for (int fn = 0; fn < 2; ++fn) {
                int t = tb + tw * 64 + fn * 32 + lo32;
                #pragma unroll
                for (int reg = 0; reg < 16; ++reg) {
                    int o = oh * 64 + fm * 32 + (reg & 3) + 8 * (reg >> 2) + 4 * kg;
                    out[(((size_t)n * 128 + o) * 128 + f) * 256 + t] = acc[fm][fn][reg] + b[o];
                }
            }
        }

        __syncthreads();                       // all waves done reading slot sA
        if (i < FPB - 1) write_row(sA);        // row f+2 replaces row f-1
        __syncthreads();                       // ring slot ready for next iter
        int tmp = sA; sA = sB; sB = sC; sC = tmp;
    }
}

extern "C" void kernel_launch(void* const* d_in, const int* in_sizes, int n_in,
                              void* d_out, int out_size, void* d_ws, size_t ws_size,
                              hipStream_t stream) {
    const float* x = (const float*)d_in[0];
    const float* W = (const float*)d_in[1];
    const float* b = (const float*)d_in[2];
    float* out = (float*)d_out;
    unsigned short* Wr = (unsigned short*)d_ws;  // 147,456 B

    hipLaunchKernelGGL(prep_w, dim3(288), dim3(256), 0, stream, W, Wr);
    hipLaunchKernelGGL(damp_conv_mfma, dim3(256), dim3(256), 0, stream, x, Wr, b, out);
}

// Round 29
// 234.096 us; speedup vs baseline: 1.6512x; 1.0866x over previous
//
#include <hip/hip_runtime.h>

typedef __attribute__((ext_vector_type(8))) short bf16x8;
typedef __attribute__((ext_vector_type(16))) float f32x16;

#define CPs  72          // shorts per t-row (64 c + 8 pad): 144B pitch, 16B-aligned b128 frags
#define ROWS 130         // 128 t + 2 halo
#define SLOT (ROWS * CPs)
#define FPB  32          // f rows swept per block (grid 256 = exactly 1 block/CU)

__device__ __forceinline__ unsigned short f2bf(float v) {
    unsigned u = __builtin_bit_cast(unsigned, v);
    return (unsigned short)((u + 0x7fffu + ((u >> 16) & 1u)) >> 16);
}

__device__ __forceinline__ float dampf(float tt) {
    return (1.0f - 0.1f * fabsf(tt - 128.f) * (1.f / 128.f))
         * (1.0f - 0.1f * fabsf(tt - 64.f) * (1.f / 64.f));
}

// ---- W reorder: [o][c][kh][kw] f32 -> [k9][ks][kg][o][8c] bf16 ----
// For a fixed (k9,ks,kg) MFMA fragment, the wave's 64 lanes now read
// CONTIGUOUS 16B chunks (o-consecutive) instead of a 32-line gather.
__global__ __launch_bounds__(256) void prep_w(const float* __restrict__ W,
                                              unsigned short* __restrict__ Wr) {
    int id = blockIdx.x * 256 + threadIdx.x;
    if (id >= 9 * 128 * 64) return;
    int j  = id & 7;
    int o  = (id >> 3) & 127;
    int kg = (id >> 10) & 1;
    int ks = (id >> 11) & 3;
    int k9 = id >> 13;
    int c  = ks * 16 + kg * 8 + j;
    Wr[id] = f2bf(W[(o * 64 + c) * 9 + k9]);
}

// ---- main conv: R28 champion body; ONLY change = af burst-layout reads ----
__global__ __launch_bounds__(256) void damp_conv_mfma(
    const float* __restrict__ x, const unsigned short* __restrict__ Wr,
    const float* __restrict__ b, float* __restrict__ out)
{
    __shared__ unsigned short xs[3 * SLOT];   // 56,160 B

    const int tid  = threadIdx.x;
    const int lane = tid & 63;
    const int wid  = tid >> 6;
    const int q    = lane & 3;
    const int p16  = lane >> 2;
    const int lo32 = lane & 31;
    const int kg   = lane >> 5;    // k-group (8 elems) within fragment

    const int raw = blockIdx.x;                        // grid 256
    const int logical = (raw & 7) * 32 + (raw >> 3);   // XCD-chunked, bijective (256%8==0)
    const int n  = logical >> 3;
    const int th = (logical >> 2) & 1;
    const int f0 = (logical & 3) * FPB;

    const int tb = th * 128;
    const int oh = wid & 1;       // wave o-half
    const int tw = wid >> 1;      // wave t-half within window

    const unsigned selv = (q & 1) ? 0x07060302u : 0x05040100u;

    float dmp[2][4];
    #pragma unroll
    for (int s = 0; s < 2; ++s)
        #pragma unroll
        for (int j = 0; j < 4; ++j)
            dmp[s][j] = dampf((float)(tb + 64 * s + 4 * p16 + j));

    // halo lanes: tid<128 covers side=(tid>>6)&1, c=tid&63
    const int hside = (tid >> 6) & 1;
    const int hc    = tid & 63;
    const int t_h   = tb + (hside ? 128 : -1);
    const bool tok  = (unsigned)t_h < 256u;
    const float dmp_h = dampf((float)(tok ? t_h : 0));

    float4 rb[8];
    float  hv;

    auto issue_row = [&](int fg) {
        const bool fok = (unsigned)fg < 128u;   // wave-uniform
        #pragma unroll
        for (int j = 0; j < 8; ++j) {
            int c = wid * 16 + (j & 3) * 4 + q;
            const float* src = x + ((size_t)(n * 64 + c) * 128 + (fok ? fg : 0)) * 256
                             + tb + (j >> 2) * 64 + 4 * p16;
            rb[j] = fok ? *(const float4*)src : (float4){0.f, 0.f, 0.f, 0.f};
        }
        hv = 0.f;
        if (tid < 128 && fok && tok)
            hv = x[((size_t)(n * 64 + hc) * 128 + fg) * 256 + t_h];
    };

    auto write_row = [&](int slot) {
        unsigned short* dstb = &xs[slot * SLOT];
        #pragma unroll
        for (int j = 0; j < 8; ++j) {
            const int s  = j >> 2;
            const int c0 = wid * 16 + (j & 3) * 4;
            float4 v = rb[j];
            unsigned d0 = (unsigned)f2bf(v.x * dmp[s][0]) | ((unsigned)f2bf(v.y * dmp[s][1]) << 16);
            unsigned d1 = (unsigned)f2bf(v.z * dmp[s][2]) | ((unsigned)f2bf(v.w * dmp[s][3]) << 16);
            // 4x4 u16 quad transpose: lane ends with c0..c0+3 at t_loc = 64s + lane
            unsigned p0 = __shfl_xor((int)d0, 2);
            unsigned p1 = __shfl_xor((int)d1, 2);
            bool hi = (lane >> 1) & 1;
            unsigned own = hi ? d1 : d0;
            unsigned oth = hi ? p1 : p0;
            unsigned sown = __shfl_xor((int)own, 1);
            unsigned soth = __shfl_xor((int)oth, 1);
            bool b0 = q & 1, b1 = q & 2;
            unsigned a0 = b0 ? sown : own, a1 = b0 ? own : sown;
            unsigned g0 = b0 ? soth : oth, g1 = b0 ? oth : soth;
            unsigned e0 = b1 ? g0 : a0, e1 = b1 ? g1 : a1;
            unsigned e2 = b1 ? a0 : g0, e3 = b1 ? a1 : g1;
            unsigned r0 = __builtin_amdgcn_perm(e1, e0, selv);
            unsigned r1 = __builtin_amdgcn_perm(e3, e2, selv);
            unsigned* dst = (unsigned*)&dstb[(1 + 64 * s + lane) * CPs + c0];
            dst[0] = r0;
            dst[1] = r1;
        }
        if (tid < 128)
            dstb[(hside ? (ROWS - 1) : 0) * CPs + hc] = f2bf(hv * dmp_h);
    };

    f32x16 acc[2][2];

    auto mfma_kh = [&](int kh, int slot) {
        const unsigned short* sb = &xs[slot * SLOT];
        #pragma unroll
        for (int kw = 0; kw < 3; ++kw) {
            #pragma unroll
            for (int ks = 0; ks < 4; ++ks) {          // K-step: 16 c per MFMA
                const int cb = ks * 16 + kg * 8;      // bx chunk base (LDS side unchanged)
                bf16x8 af[2];
                #pragma unroll
                for (int fm = 0; fm < 2; ++fm) {
                    int o = oh * 64 + fm * 32 + lo32;
                    // burst layout: [k9][ks][kg][o][8c] -> lanes read contiguous 16B chunks
                    af[fm] = *(const bf16x8*)(Wr + (((((kh * 3 + kw) * 4 + ks) * 2 + kg) * 128 + o) << 3));
                }
                #pragma unroll
                for (int fn = 0; fn < 2; ++fn) {
                    int row = tw * 64 + fn * 32 + lo32 + kw;
                    // single 16B-aligned ds_read_b128 (R17-verified conflict-free)
                    bf16x8 bx = *(const bf16x8*)&sb[row * CPs + cb];
                    #pragma unroll
                    for (int fm = 0; fm < 2; ++fm)
                        acc[fm][fn] = __builtin_amdgcn_mfma_f32_32x32x16_bf16(
                            af[fm], bx, acc[fm][fn], 0, 0, 0);
                }
            }
        }
    };

    // ---- prologue: stage rows f0-1, f0, f0+1 into slots 0,1,2 ----
    issue_row(f0 - 1); write_row(0);
    issue_row(f0);     write_row(1);
    issue_row(f0 + 1); write_row(2);
    __syncthreads();

    int sA = 0, sB = 1, sC = 2;   // slots of rows f-1, f, f+1

    #pragma unroll 1
    for (int i = 0; i < FPB; ++i) {
        const int f = f0 + i;
        if (i < FPB - 1) issue_row(f + 2);   // loads in flight under this iter's MFMAs

        #pragma unroll
        for (int a = 0; a < 2; ++a)
            #pragma unroll
            for (int c2 = 0; c2 < 2; ++c2)
                #pragma unroll
                for (int e = 0; e < 16; ++e) acc[a][c2][e] = 0.f;

        mfma_kh(0, sA);
        mfma_kh(1, sB);
        mfma_kh(2, sC);

        // epilogue: C/D layout col=lane&31 (t), row=(reg&3)+8*(reg>>2)+4*(lane>>5)
        #pragma unroll
        for (int fm = 0; fm < 2; ++fm) {
            #pragma unroll
            for (int fn = 0; fn < 2; ++fn) {
                int t = tb + tw * 64 + fn * 32 + lo32;
                #pragma unroll
                for (int reg = 0; reg < 16; ++reg) {
                    int o = oh * 64 + fm * 32 + (reg & 3) + 8 * (reg >> 2) + 4 * kg;
                    out[(((size_t)n * 128 + o) * 128 + f) * 256 + t] = acc[fm][fn][reg] + b[o];
                }
            }
        }

        __syncthreads();                       // all waves done reading slot sA
        if (i < FPB - 1) write_row(sA);        // row f+2 replaces row f-1
        __syncthreads();                       // ring slot ready for next iter
        int tmp = sA; sA = sB; sB = sC; sC = tmp;
    }
}

extern "C" void kernel_launch(void* const* d_in, const int* in_sizes, int n_in,
                              void* d_out, int out_size, void* d_ws, size_t ws_size,
                              hipStream_t stream) {
    const float* x = (const float*)d_in[0];
    const float* W = (const float*)d_in[1];
    const float* b = (const float*)d_in[2];
    float* out = (float*)d_out;
    unsigned short* Wr = (unsigned short*)d_ws;  // 147,456 B

    hipLaunchKernelGGL(prep_w, dim3(288), dim3(256), 0, stream, W, Wr);
    hipLaunchKernelGGL(damp_conv_mfma, dim3(256), dim3(256), 0, stream, x, Wr, b, out);
}